// Round 4
// baseline (186.513 us; speedup 1.0000x reference)
//
#include <hip/hip_runtime.h>
#include <math.h>

#define S_SPOTS 2048
#define B_BINS 3000
#define E_EDGES 12288
#define SB_TOTAL (S_SPOTS * B_BINS)   /* 6,144,000 */
#define SB4 (SB_TOTAL / 4)            /* 1,536,000 map threads */
#define ROW_BYTES 768                 /* 750 data bytes + 18 pad (never read) */
#define ROW_DW 192
#define ST_BYTES (S_SPOTS * ROW_BYTES) /* 1,572,864 */
#define NSLOT 64

// ws layout:
//   [0, ST_BYTES)                  packed 2-bit states, 768 B rows
//   [ST_BYTES, +NSLOT*64)          64 counter slots, one per 64B line
//   [ST_BYTES + NSLOT*64, +4)      done counter
// Slots+done are zeroed by map_kernel block 0 (stream order => visible
// to edge_kernel). State-table pad bytes are never read by edge_kernel,
// so no memset of the table is needed.

__global__ __launch_bounds__(256) void map_kernel(
        const float4* __restrict__ x4,
        const float4* __restrict__ g4,
        const float* __restrict__ state_means,
        const float* __restrict__ log_stds,
        float4* __restrict__ out4,
        unsigned char* __restrict__ st,
        unsigned int* __restrict__ slots) {
    __shared__ float4 lg[768];     // 12 KB gumbel tile
    __shared__ double sp[6];
    int tid = threadIdx.x;
    int blk = blockIdx.x;

    if (blk == 0 && tid <= NSLOT) slots[tid * 16] = 0u;  // 64 slots + done
    if (tid == 0) {
        const double CHALF = 0.9189385332046727;
        for (int k = 0; k < 3; ++k) {
            // numpy-f64 sequence: std = exp(ls)+1e-6 ; recip-mul ~1ulp
            double sd = exp((double)log_stds[k]) + 1e-6;
            sp[k]     = 1.0 / sd;
            sp[3 + k] = -log(sd) - CHALF;
        }
    }
    // coalesced staging: block's 3072 gumbel floats = 768 float4
    const float4* gg = g4 + (size_t)blk * 768;
    float4 t0 = gg[tid];
    float4 t1 = gg[tid + 256];
    float4 t2 = gg[tid + 512];
    int gi = blk * 256 + tid;
    float4 xv = x4[gi];
    float m0f = state_means[0];
    float m2f = state_means[1];
    lg[tid] = t0; lg[tid + 256] = t1; lg[tid + 512] = t2;
    __syncthreads();

    double r0 = sp[0], r1 = sp[1], r2 = sp[2];
    double cc0 = sp[3], cc1 = sp[4], cc2 = sp[5];
    double m0 = (double)m0f, m2 = (double)m2f;

    const float4* myg = (const float4*)((const char*)lg + 48 * tid);
    float4 ga = myg[0], gb = myg[1], gc = myg[2];
    float xs[4]  = {xv.x, xv.y, xv.z, xv.w};
    float gs[12] = {ga.x, ga.y, ga.z, ga.w, gb.x, gb.y, gb.z, gb.w,
                    gc.x, gc.y, gc.z, gc.w};
    float os[4];
    unsigned pk = 0;
#pragma unroll
    for (int j = 0; j < 4; ++j) {
        double x = (double)xs[j];
        // f64 logits, <=2ulp vs numpy-f64 ref; argmax-safe
        double z0 = (x - m0) * r0;
        double z1 = x * r1;
        double z2 = (x - m2) * r2;
        double l0 = fma(-0.5 * z0, z0, cc0) + (double)gs[3 * j + 0];
        double l1 = fma(-0.5 * z1, z1, cc1) + (double)gs[3 * j + 1];
        double l2 = fma(-0.5 * z2, z2, cc2) + (double)gs[3 * j + 2];
        int k = 0; double best = l0;
        if (l1 > best) { best = l1; k = 1; }
        if (l2 > best) { best = l2; k = 2; }
        os[j] = (k == 0) ? m0f : ((k == 1) ? 0.0f : m2f);
        pk |= (unsigned)k << (2 * j);
    }
    out4[gi] = make_float4(os[0], os[1], os[2], os[3]);
    // packed 2-bit store: 4 bins/byte; each thread's 4 bins share one row
    unsigned sb0  = 4u * (unsigned)gi;
    unsigned row  = sb0 / 3000u;          // const divisor -> magic mul
    unsigned colb = (sb0 % 3000u) >> 2;
    st[row * ROW_BYTES + colb] = (unsigned char)pk;
}

__global__ __launch_bounds__(512) void edge_kernel(
        const int* __restrict__ edge_index,
        const unsigned int* __restrict__ st,   // dword view of packed table
        unsigned int* __restrict__ slots,      // 64 slots, 64B apart; +done
        float* __restrict__ out) {
    int lane = threadIdx.x & 63;
    int wid  = threadIdx.x >> 6;               // 8 waves/block
    int e    = blockIdx.x * 8 + wid;           // one edge per wave
    // broadcast loads (all lanes same address)
    int r = edge_index[e];
    int c = edge_index[E_EDGES + e];
    const unsigned* pr = st + r * ROW_DW;
    const unsigned* pc = st + c * ROW_DW;
    // 6 independent coalesced loads; dwords 0..187 hold data, 187 is half
    unsigned a0 = pr[lane], b0 = pc[lane];
    unsigned a1 = pr[lane + 64], b1 = pc[lane + 64];
    unsigned a2 = 0, b2 = 0;
    if (lane < 60) { a2 = pr[lane + 128]; b2 = pc[lane + 128]; }
    unsigned v0 = a0 ^ b0, v1 = a1 ^ b1, v2 = a2 ^ b2;
    if (lane == 59) v2 &= 0x0000FFFFu;         // dword 187: pad in top bytes
    // nonzero 2-bit group => states differ at that bin
    unsigned cnt = (unsigned)__popc((v0 | (v0 >> 1)) & 0x55555555u)
                 + (unsigned)__popc((v1 | (v1 >> 1)) & 0x55555555u)
                 + (unsigned)__popc((v2 | (v2 >> 1)) & 0x55555555u);
    for (int off = 32; off; off >>= 1)
        cnt += __shfl_down(cnt, off, 64);
    __shared__ unsigned wsum[8];
    if (lane == 0) wsum[wid] = cnt;
    __syncthreads();
    if (threadIdx.x == 0) {
        unsigned bs = 0;
#pragma unroll
        for (int w = 0; w < 8; ++w) bs += wsum[w];
        // scatter across 64 one-line-apart slots: ~24 atomics/line, pipelined
        atomicAdd(&slots[(blockIdx.x & (NSLOT - 1)) * 16], bs);
        __threadfence();
        unsigned old = atomicAdd(&slots[NSLOT * 16], 1u);   // done counter
        if (old == gridDim.x - 1) {                          // last block
            __threadfence();
            unsigned total = 0;
            for (int s = 0; s < NSLOT; ++s)
                total += atomicAdd(&slots[s * 16], 0u);      // coherent read
            // each mismatching (edge,bin) contributes exactly 2.0
            double sum  = 2.0 * (double)total;
            double mean = sum / ((double)E_EDGES * (double)B_BINS * 3.0);
            out[SB_TOTAL] = (float)(0.1 * mean);             // LAMBDA_SMOOTH
        }
    }
}

extern "C" void kernel_launch(void* const* d_in, const int* in_sizes, int n_in,
                              void* d_out, int out_size, void* d_ws, size_t ws_size,
                              hipStream_t stream) {
    const float* x           = (const float*)d_in[0];
    /* d_in[1] = bin_idx — arange(B) identity gather, no-op */
    const int*   edge_index  = (const int*)d_in[2];
    const float* gumbel      = (const float*)d_in[3];
    const float* state_means = (const float*)d_in[4];
    const float* log_stds    = (const float*)d_in[5];
    float* out = (float*)d_out;

    unsigned char* st    = (unsigned char*)d_ws;
    unsigned int*  slots = (unsigned int*)((char*)d_ws + ST_BYTES);

    map_kernel<<<SB4 / 256, 256, 0, stream>>>(
        (const float4*)x, (const float4*)gumbel, state_means, log_stds,
        (float4*)d_out, st, slots);
    edge_kernel<<<E_EDGES / 8, 512, 0, stream>>>(
        edge_index, (const unsigned int*)st, slots, out);
}

// Round 5
// 145.045 us; speedup vs baseline: 1.2859x; 1.2859x over previous
//
#include <hip/hip_runtime.h>
#include <math.h>

#define S_SPOTS 2048
#define B_BINS 3000
#define E_EDGES 12288
#define SB_TOTAL (S_SPOTS * B_BINS)   /* 6,144,000 */
#define SB4 (SB_TOTAL / 4)            /* 1,536,000 map threads */
#define ROW_BYTES 768                 /* 750 data bytes + 18 pad (never read) */
#define ROW_DW 192
#define ST_BYTES (S_SPOTS * ROW_BYTES) /* 1,572,864 */
#define NSLOT 64

// ws layout:
//   [0, ST_BYTES)              packed 2-bit states, 768 B rows
//   [ST_BYTES, +NSLOT*64)      64 counter slots, one per 64B line
// Slots zeroed by map_kernel block 0 (stream order => visible to edge).
// Max same-address atomic traffic: 768 blocks / 64 slots = 12 RMWs/address
// (~30ns each serialized => <0.5us; the round-4 'done' counter at 1536
// RMWs/address was the 46us stall).

__global__ __launch_bounds__(256) void map_kernel(
        const float4* __restrict__ x4,
        const float4* __restrict__ g4,
        const float* __restrict__ state_means,
        const float* __restrict__ log_stds,
        float4* __restrict__ out4,
        unsigned char* __restrict__ st,
        unsigned int* __restrict__ slots) {
    __shared__ float4 lg[768];     // 12 KB gumbel tile
    __shared__ double sp[6];
    int tid = threadIdx.x;
    int blk = blockIdx.x;

    if (blk == 0 && tid < NSLOT) slots[tid * 16] = 0u;
    if (tid == 0) {
        const double CHALF = 0.9189385332046727;
        for (int k = 0; k < 3; ++k) {
            // numpy-f64 sequence: std = exp(ls)+1e-6 ; recip-mul ~1ulp
            double sd = exp((double)log_stds[k]) + 1e-6;
            sp[k]     = 1.0 / sd;
            sp[3 + k] = -log(sd) - CHALF;
        }
    }
    // coalesced staging: block's 3072 gumbel floats = 768 float4
    const float4* gg = g4 + (size_t)blk * 768;
    float4 t0 = gg[tid];
    float4 t1 = gg[tid + 256];
    float4 t2 = gg[tid + 512];
    int gi = blk * 256 + tid;
    float4 xv = x4[gi];
    float m0f = state_means[0];
    float m2f = state_means[1];
    lg[tid] = t0; lg[tid + 256] = t1; lg[tid + 512] = t2;
    __syncthreads();

    double r0 = sp[0], r1 = sp[1], r2 = sp[2];
    double cc0 = sp[3], cc1 = sp[4], cc2 = sp[5];
    double m0 = (double)m0f, m2 = (double)m2f;

    const float4* myg = (const float4*)((const char*)lg + 48 * tid);
    float4 ga = myg[0], gb = myg[1], gc = myg[2];
    float xs[4]  = {xv.x, xv.y, xv.z, xv.w};
    float gs[12] = {ga.x, ga.y, ga.z, ga.w, gb.x, gb.y, gb.z, gb.w,
                    gc.x, gc.y, gc.z, gc.w};
    float os[4];
    unsigned pk = 0;
#pragma unroll
    for (int j = 0; j < 4; ++j) {
        double x = (double)xs[j];
        // f64 logits, <=2ulp vs numpy-f64 ref; argmax-safe
        double z0 = (x - m0) * r0;
        double z1 = x * r1;
        double z2 = (x - m2) * r2;
        double l0 = fma(-0.5 * z0, z0, cc0) + (double)gs[3 * j + 0];
        double l1 = fma(-0.5 * z1, z1, cc1) + (double)gs[3 * j + 1];
        double l2 = fma(-0.5 * z2, z2, cc2) + (double)gs[3 * j + 2];
        int k = 0; double best = l0;
        if (l1 > best) { best = l1; k = 1; }
        if (l2 > best) { best = l2; k = 2; }
        os[j] = (k == 0) ? m0f : ((k == 1) ? 0.0f : m2f);
        pk |= (unsigned)k << (2 * j);
    }
    out4[gi] = make_float4(os[0], os[1], os[2], os[3]);
    // packed 2-bit store: 4 bins/byte; each thread's 4 bins share one row
    unsigned sb0  = 4u * (unsigned)gi;
    unsigned row  = sb0 / 3000u;          // const divisor -> magic mul
    unsigned colb = (sb0 % 3000u) >> 2;
    st[row * ROW_BYTES + colb] = (unsigned char)pk;
}

__global__ __launch_bounds__(512) void edge_kernel(
        const int* __restrict__ edge_index,
        const unsigned int* __restrict__ st,   // dword view of packed table
        unsigned int* __restrict__ slots) {    // 64 slots, 64B apart
    int lane = threadIdx.x & 63;
    int wid  = threadIdx.x >> 6;               // 8 waves/block
    int gw   = blockIdx.x * 8 + wid;           // 6144 waves x 2 edges
    int e0 = 2 * gw, e1 = 2 * gw + 1;
    int r0 = edge_index[e0], c0 = edge_index[E_EDGES + e0];
    int r1 = edge_index[e1], c1 = edge_index[E_EDGES + e1];
    const unsigned* pr0 = st + r0 * ROW_DW;
    const unsigned* pc0 = st + c0 * ROW_DW;
    const unsigned* pr1 = st + r1 * ROW_DW;
    const unsigned* pc1 = st + c1 * ROW_DW;
    // 12 independent coalesced 256B loads (L2-resident table)
    unsigned a0 = pr0[lane],      b0 = pc0[lane];
    unsigned a1 = pr0[lane + 64], b1 = pc0[lane + 64];
    unsigned d0 = pr1[lane],      f0 = pc1[lane];
    unsigned d1 = pr1[lane + 64], f1 = pc1[lane + 64];
    unsigned a2 = 0, b2 = 0, d2 = 0, f2 = 0;
    if (lane < 60) {                           // dwords 128..187 hold data
        a2 = pr0[lane + 128]; b2 = pc0[lane + 128];
        d2 = pr1[lane + 128]; f2 = pc1[lane + 128];
    }
    unsigned v0 = a0 ^ b0, v1 = a1 ^ b1, v2 = a2 ^ b2;
    unsigned w0 = d0 ^ f0, w1 = d1 ^ f1, w2 = d2 ^ f2;
    if (lane == 59) { v2 &= 0x0000FFFFu; w2 &= 0x0000FFFFu; }  // row pad
    // nonzero 2-bit group => states differ at that bin
    unsigned cnt = (unsigned)__popc((v0 | (v0 >> 1)) & 0x55555555u)
                 + (unsigned)__popc((v1 | (v1 >> 1)) & 0x55555555u)
                 + (unsigned)__popc((v2 | (v2 >> 1)) & 0x55555555u)
                 + (unsigned)__popc((w0 | (w0 >> 1)) & 0x55555555u)
                 + (unsigned)__popc((w1 | (w1 >> 1)) & 0x55555555u)
                 + (unsigned)__popc((w2 | (w2 >> 1)) & 0x55555555u);
    for (int off = 32; off; off >>= 1)
        cnt += __shfl_down(cnt, off, 64);
    __shared__ unsigned wsum[8];
    if (lane == 0) wsum[wid] = cnt;
    __syncthreads();
    if (threadIdx.x == 0) {
        unsigned bs = 0;
#pragma unroll
        for (int w = 0; w < 8; ++w) bs += wsum[w];
        atomicAdd(&slots[(blockIdx.x & (NSLOT - 1)) * 16], bs);
    }
}

__global__ void fin_kernel(const unsigned int* __restrict__ slots,
                           float* __restrict__ out) {
    // kernel dispatch boundary = release/acquire; plain loads see atomics
    unsigned v = slots[threadIdx.x * 16];      // 64 threads, 64 slots
    for (int off = 32; off; off >>= 1)
        v += __shfl_down(v, off, 64);
    if (threadIdx.x == 0) {
        // each mismatching (edge,bin) contributes exactly 2.0
        double sum  = 2.0 * (double)v;
        double mean = sum / ((double)E_EDGES * (double)B_BINS * 3.0);
        out[SB_TOTAL] = (float)(0.1 * mean);   // LAMBDA_SMOOTH
    }
}

extern "C" void kernel_launch(void* const* d_in, const int* in_sizes, int n_in,
                              void* d_out, int out_size, void* d_ws, size_t ws_size,
                              hipStream_t stream) {
    const float* x           = (const float*)d_in[0];
    /* d_in[1] = bin_idx — arange(B) identity gather, no-op */
    const int*   edge_index  = (const int*)d_in[2];
    const float* gumbel      = (const float*)d_in[3];
    const float* state_means = (const float*)d_in[4];
    const float* log_stds    = (const float*)d_in[5];
    float* out = (float*)d_out;

    unsigned char* st    = (unsigned char*)d_ws;
    unsigned int*  slots = (unsigned int*)((char*)d_ws + ST_BYTES);

    map_kernel<<<SB4 / 256, 256, 0, stream>>>(
        (const float4*)x, (const float4*)gumbel, state_means, log_stds,
        (float4*)d_out, st, slots);
    edge_kernel<<<E_EDGES / 16, 512, 0, stream>>>(
        edge_index, (const unsigned int*)st, slots);
    fin_kernel<<<1, 64, 0, stream>>>(slots, out);
}